// Round 2
// baseline (1543.084 us; speedup 1.0000x reference)
//
#include <hip/hip_runtime.h>
#include <stdint.h>

typedef _Float16 f16;
typedef _Float16 f16x8 __attribute__((ext_vector_type(8)));
typedef _Float16 f16x4 __attribute__((ext_vector_type(4)));
typedef float f32x4 __attribute__((ext_vector_type(4)));

__device__ __forceinline__ void gload_lds16(const void* g, void* l) {
    __builtin_amdgcn_global_load_lds(
        (const __attribute__((address_space(1))) unsigned int*)g,
        (__attribute__((address_space(3))) unsigned int*)l, 16, 0, 0);
}

#define VMWAIT(n) asm volatile("s_waitcnt vmcnt(" #n ")" ::: "memory")
#define MEMFENCE  asm volatile("" ::: "memory")

// ---------------------------------------------------------------------------
__global__ __launch_bounds__(256) void cvt_f32_f16(const float* __restrict__ s,
                                                   f16* __restrict__ d, int n8) {
    int i = blockIdx.x * 256 + threadIdx.x;
    if (i >= n8) return;
    const float4* s4 = (const float4*)s;
    float4 a = s4[2 * (size_t)i];
    float4 b = s4[2 * (size_t)i + 1];
    f16x8 o;
    o[0] = (f16)a.x; o[1] = (f16)a.y; o[2] = (f16)a.z; o[3] = (f16)a.w;
    o[4] = (f16)b.x; o[5] = (f16)b.y; o[6] = (f16)b.z; o[7] = (f16)b.w;
    *(f16x8*)(d + (size_t)i * 8) = o;
}

// ---------------------------------------------------------------------------
// 256x256 BT-GEMM, BK=32, 512 threads = 8 waves (2x4), 4-deep LDS ring
// (128 KiB dynamic), counted vmcnt (8 steady), T2 swizzle, T5 setprio,
// T1 bijective XCD swizzle on a linearized grid.
// C[m,n] = alpha * sum_k A[m,k]*B[n,k]; batch z -> (h=z/NB, b=z%NB).
template <typename OutT>
__global__ __launch_bounds__(512, 2) void gemm256(
    const f16* __restrict__ A, const f16* __restrict__ B, OutT* __restrict__ C,
    int ldA, int ldB, long long ldC, int K, float alpha,
    long long sAh, long long sAb, long long sBh, long long sBb,
    long long sCh, long long sCb, int NB, int gx, int gy) {
    extern __shared__ char lds[];
    char* ldsA = lds;             // 4 bufs x 16 KB
    char* ldsB = lds + 65536;     // 4 bufs x 16 KB

    // bijective XCD swizzle (m204): co-locate consecutive logical blocks
    const int nwg = gridDim.x;
    const int q = nwg >> 3, r = nwg & 7;
    const int xcd = blockIdx.x & 7, lid = blockIdx.x >> 3;
    const int wg = (xcd < r ? xcd * (q + 1) : r * (q + 1) + (xcd - r) * q) + lid;
    const int z = wg / (gx * gy);
    const int rem = wg - z * (gx * gy);
    const int by = rem / gx, bx = rem - by * gx;
    const int h = z / NB, bb = z - h * NB;
    A += h * sAh + bb * sAb;
    B += h * sBh + bb * sBb;
    C += h * sCh + bb * sCb;
    const int row0 = by * 256, col0 = bx * 256;

    const int tid  = threadIdx.x;
    const int lane = tid & 63;
    const int wid  = tid >> 6;
    const int wm   = wid >> 2;          // 0..1 -> rows wm*128
    const int wn   = wid & 3;           // 0..3 -> cols wn*64
    const int fr   = lane & 15;
    const int fkb  = (lane >> 4) << 4;  // k byte offset in row (0/16/32/48)

    // swizzled ds_read byte offsets within one 16 KB buffer (64 B rows)
    int offA[8], offB[4];
#pragma unroll
    for (int i = 0; i < 8; ++i) {
        int row = wm * 128 + i * 16 + fr;
        offA[i] = row * 64 + (fkb ^ (((row >> 1) & 3) << 4));
    }
#pragma unroll
    for (int j = 0; j < 4; ++j) {
        int row = wn * 64 + j * 16 + fr;
        offB[j] = row * 64 + (fkb ^ (((row >> 1) & 3) << 4));
    }

    // staging: linear LDS dest (wave-uniform base + lane*16), inverse-swizzled
    // global source. thread -> (row = c*128 + tid/4, 16B slot = tid%4).
    const int srow  = tid >> 2;
    const int sbyte = (tid & 3) << 4;
    const int scol  = (sbyte ^ (((srow >> 1) & 3) << 4)) >> 1;  // element col
    const f16* gA0 = A + (size_t)(row0 + srow) * ldA + scol;
    const f16* gA1 = A + (size_t)(row0 + 128 + srow) * ldA + scol;
    const f16* gB0 = B + (size_t)(col0 + srow) * ldB + scol;
    const f16* gB1 = B + (size_t)(col0 + 128 + srow) * ldB + scol;
    char* lA0 = ldsA + tid * 16;
    char* lB0 = ldsB + tid * 16;

    const int nkt = K >> 5;

#define STAGE(tt) do { \
        const int _bo = ((tt) & 3) << 14; \
        const size_t _ko = (size_t)(tt) * 32; \
        gload_lds16(gA0 + _ko, lA0 + _bo); \
        gload_lds16(gA1 + _ko, lA0 + _bo + 8192); \
        gload_lds16(gB0 + _ko, lB0 + _bo); \
        gload_lds16(gB1 + _ko, lB0 + _bo + 8192); \
    } while (0)

    STAGE(0); STAGE(1); STAGE(2);   // 12 loads in flight

    f32x4 acc[8][4] = {};

    for (int t = 0; t < nkt; ++t) {
        // wait for tile t only; keep up to 2 future tiles (8 loads) in flight
        if (t < nkt - 2)       VMWAIT(8);
        else if (t == nkt - 2) VMWAIT(4);
        else                   VMWAIT(0);
        __builtin_amdgcn_s_barrier();
        MEMFENCE;
        if (t + 3 < nkt) STAGE(t + 3);  // overwrites buf[(t-1)&3]: safe after barrier
        const char* bA = ldsA + ((t & 3) << 14);
        const char* bB = ldsB + ((t & 3) << 14);
        f16x8 af[8], bf[4];
#pragma unroll
        for (int i = 0; i < 8; ++i) af[i] = *(const f16x8*)(bA + offA[i]);
#pragma unroll
        for (int j = 0; j < 4; ++j) bf[j] = *(const f16x8*)(bB + offB[j]);
        __builtin_amdgcn_s_setprio(1);
#pragma unroll
        for (int i = 0; i < 8; ++i)
#pragma unroll
            for (int j = 0; j < 4; ++j)
                acc[i][j] = __builtin_amdgcn_mfma_f32_16x16x32_f16(
                    af[i], bf[j], acc[i][j], 0, 0, 0);
        __builtin_amdgcn_s_setprio(0);
    }
#undef STAGE

    // C/D layout: col = lane&15, row = (lane>>4)*4 + reg
    const int er = (lane >> 4) * 4;
#pragma unroll
    for (int i = 0; i < 8; ++i)
#pragma unroll
        for (int j = 0; j < 4; ++j)
#pragma unroll
            for (int rr = 0; rr < 4; ++rr) {
                size_t idx = (size_t)(row0 + wm * 128 + i * 16 + er + rr) * (size_t)ldC +
                             (size_t)(col0 + wn * 64 + j * 16 + fr);
                C[idx] = (OutT)(acc[i][j][rr] * alpha);
            }
}

// ---------------------------------------------------------------------------
__global__ __launch_bounds__(256) void reduce_split4(const float* __restrict__ p,
                                                     float* __restrict__ o, int n4) {
    int i = blockIdx.x * 256 + threadIdx.x;
    if (i >= n4) return;
    const float4* p4 = (const float4*)p;
    float4 a = p4[i], b = p4[i + 1048576], c = p4[i + 2097152], d = p4[i + 3145728];
    float4 s;
    s.x = a.x + b.x + c.x + d.x;
    s.y = a.y + b.y + c.y + d.y;
    s.z = a.z + b.z + c.z + d.z;
    s.w = a.w + b.w + c.w + d.w;
    ((float4*)o)[i] = s;
}

// ---------------------------------------------------------------------------
__global__ __launch_bounds__(256) void softmax_rows(f16* __restrict__ P) {
    const size_t row = blockIdx.x;
    f16* p = P + row * 1024;
    const int tid = threadIdx.x, lane = tid & 63, wid = tid >> 6;

    f16x4 v4 = *(const f16x4*)(p + tid * 4);
    float v[4];
#pragma unroll
    for (int t = 0; t < 4; ++t) {
        v[t] = (float)v4[t];
        if (v[t] == 0.0f) v[t] = -9e15f;
    }
    float m = fmaxf(fmaxf(v[0], v[1]), fmaxf(v[2], v[3]));
#pragma unroll
    for (int o = 32; o > 0; o >>= 1) m = fmaxf(m, __shfl_xor(m, o));
    __shared__ float red[8];
    if (lane == 0) red[wid] = m;
    __syncthreads();
    m = fmaxf(fmaxf(red[0], red[1]), fmaxf(red[2], red[3]));

    float e[4], s = 0.f;
#pragma unroll
    for (int t = 0; t < 4; ++t) { e[t] = __expf(v[t] - m); s += e[t]; }
#pragma unroll
    for (int o = 32; o > 0; o >>= 1) s += __shfl_xor(s, o);
    if (lane == 0) red[4 + wid] = s;
    __syncthreads();
    s = red[4] + red[5] + red[6] + red[7];
    float inv = 1.0f / s;

    f16x4 o4;
#pragma unroll
    for (int t = 0; t < 4; ++t) o4[t] = (f16)(e[t] * inv);
    *(f16x4*)(p + tid * 4) = o4;
}

// ---------------------------------------------------------------------------
extern "C" void kernel_launch(void* const* d_in, const int* in_sizes, int n_in,
                              void* d_out, int out_size, void* d_ws, size_t ws_size,
                              hipStream_t stream) {
    const float* q  = (const float*)d_in[0];
    const float* k  = (const float*)d_in[1];
    const float* v  = (const float*)d_in[2];
    const float* Wq = (const float*)d_in[3];
    const float* Wk = (const float*)d_in[4];
    const float* Wv = (const float*)d_in[5];
    const float* Wl = (const float*)d_in[6];
    float* out = (float*)d_out;

    // allow >64KB dynamic LDS (ignore errors; ROCm may not require it)
    (void)hipFuncSetAttribute((const void*)gemm256<f16>,
                              hipFuncAttributeMaxDynamicSharedMemorySize, 131072);
    (void)hipFuncSetAttribute((const void*)gemm256<float>,
                              hipFuncAttributeMaxDynamicSharedMemorySize, 131072);

    const size_t MB = 1024ull * 1024ull;
    char* ws = (char*)d_ws;
    f16* q_h  = (f16*)(ws + 0 * MB);
    f16* k_h  = (f16*)(ws + 8 * MB);
    f16* v_h  = (f16*)(ws + 16 * MB);
    f16* Wq_h = (f16*)(ws + 24 * MB);
    f16* Wk_h = (f16*)(ws + 40 * MB);
    f16* Wv_h = (f16*)(ws + 56 * MB);
    f16* Wl_h = (f16*)(ws + 72 * MB);

    cvt_f32_f16<<<2048, 256, 0, stream>>>(q, q_h, 524288);
    cvt_f32_f16<<<2048, 256, 0, stream>>>(k, k_h, 524288);
    cvt_f32_f16<<<2048, 256, 0, stream>>>(v, v_h, 524288);
    cvt_f32_f16<<<4096, 256, 0, stream>>>(Wq, Wq_h, 1048576);
    cvt_f32_f16<<<4096, 256, 0, stream>>>(Wk, Wk_h, 1048576);
    cvt_f32_f16<<<4096, 256, 0, stream>>>(Wv, Wv_h, 1048576);
    cvt_f32_f16<<<4096, 256, 0, stream>>>(Wl, Wl_h, 1048576);

    const long long M1 = 1048576ll;   // S*D
    const long long M4 = 4194304ll;   // B*S*D
    const float SCALE = 0.03125f;     // 1/sqrt(1024)
    const size_t SMEM = 131072;

    if (ws_size >= 344ull * MB) {
        f16* in_q  = (f16*)(ws + 88 * MB);
        f16* in_k  = (f16*)(ws + 152 * MB);
        f16* in_vT = (f16*)(ws + 216 * MB);
        f16* P     = (f16*)(ws + 280 * MB);
        f16* h_cat = (f16*)(ws + 88 * MB);   // aliases in_q (dead after logits)
        float* part = (float*)(ws + 280 * MB);  // aliases P (dead after PV)

        gemm256<f16><<<512, 512, SMEM, stream>>>(
            q_h, Wq_h, in_q, 1024, 1024, 1024, 1024, 1.0f,
            0, 0, M1, 0, M4, 0, 1, 4, 16);
        gemm256<f16><<<512, 512, SMEM, stream>>>(
            k_h, Wk_h, in_k, 1024, 1024, 1024, 1024, 1.0f,
            0, 0, M1, 0, M4, 0, 1, 4, 16);
        gemm256<f16><<<512, 512, SMEM, stream>>>(
            Wv_h, v_h, in_vT, 1024, 1024, 1024, 1024, 1.0f,
            M1, 0, 0, M1, M4, M1, 4, 4, 4);
        gemm256<f16><<<512, 512, SMEM, stream>>>(
            in_q, in_k, P, 1024, 1024, 1024, 1024, SCALE,
            M4, M1, M4, M1, M4, M1, 4, 4, 4);
        softmax_rows<<<32768, 256, 0, stream>>>(P);
        gemm256<f16><<<512, 512, SMEM, stream>>>(
            P, in_vT, h_cat, 1024, 1024, 8192, 1024, 1.0f,
            M4, M1, M4, M1, 1024ll, 8388608ll, 4, 4, 4);
        // last dense: split-K=4 (K=2048 each) into f32 partials, then reduce
        gemm256<float><<<256, 512, SMEM, stream>>>(
            h_cat, Wl_h, part, 8192, 8192, 1024, 2048, 1.0f,
            0, 2048, 0, 2048, 0, 4194304ll, 4, 4, 16);
        reduce_split4<<<4096, 256, 0, stream>>>(part, out, 1048576);
    } else {
        // chunked-by-head fallback (needs 184MB)
        f16* in_q  = (f16*)(ws + 88 * MB);
        f16* in_k  = (f16*)(ws + 96 * MB);
        f16* in_vT = (f16*)(ws + 104 * MB);
        f16* P     = (f16*)(ws + 112 * MB);
        f16* h_cat = (f16*)(ws + 120 * MB);
        for (int h = 0; h < 8; ++h) {
            gemm256<f16><<<64, 512, SMEM, stream>>>(
                q_h, Wq_h + h * M1, in_q, 1024, 1024, 1024, 1024, 1.0f,
                0, 0, 0, 0, 0, 0, 1, 4, 16);
            gemm256<f16><<<64, 512, SMEM, stream>>>(
                k_h, Wk_h + h * M1, in_k, 1024, 1024, 1024, 1024, 1.0f,
                0, 0, 0, 0, 0, 0, 1, 4, 16);
            gemm256<f16><<<64, 512, SMEM, stream>>>(
                Wv_h + h * M1, v_h, in_vT, 1024, 1024, 1024, 1024, 1.0f,
                0, 0, 0, M1, 0, M1, 4, 4, 4);
            gemm256<f16><<<64, 512, SMEM, stream>>>(
                in_q, in_k, P, 1024, 1024, 1024, 1024, SCALE,
                0, M1, 0, M1, 0, M1, 4, 4, 4);
            softmax_rows<<<4096, 256, 0, stream>>>(P);
            gemm256<f16><<<64, 512, SMEM, stream>>>(
                P, in_vT, h_cat + h * 1024, 1024, 1024, 8192, 1024, 1.0f,
                0, M1, 0, M1, 0, 8388608ll, 4, 4, 4);
        }
        gemm256<float><<<64, 512, SMEM, stream>>>(
            h_cat, Wl_h, out, 8192, 8192, 1024, 8192, 1.0f,
            0, 0, 0, 0, 0, 0, 1, 4, 16);
    }
}